// Round 9
// baseline (290.617 us; speedup 1.0000x reference)
//
#include <hip/hip_runtime.h>

// GraphSAGE 3-layer forward, MI355X. Round 18 (= R17 + gather widening):
//   R17 = 265.5us. layerZ FETCH 83.7MB vs ~17 mandatory => ~67MB is L2-miss
//   refill of gather rows from L3 at ~1.75 TB/s (per-CU outstanding-miss
//   limited; H 12.8MB > 4MB/XCD L2 -> ~30% hit). This round: raise per-wave
//   miss concurrency without touching structure:
//   - gather reads widened to 16 lanes x f16x8 (16B/lane), 2 edges/instr;
//     halves VMEM+index instructions; one 8x shfl_xor(16) reduce PER NODE;
//     LDS frag write becomes a single clean f16x8 per lane.
//   - fused kernels lb(256,8)->(256,6): VGPR cap 64->~85 so the 8 widened
//     loads + 8 accumulators stay in flight (R17 VGPR=32 => compiler was
//     serializing). gather64: widened f16x4 x 2-edges + lb(256,8).
//   Null result here => L3->L2 line path is the bound; next = XCD-sharded
//   column-blocked H.

constexpr int N = 50000;
constexpr int E = 800000;
constexpr int NBUCK = (N + 255) / 256;    // 196 dst-buckets (256 nodes each)
constexpr int CE = 4096;                  // edges per scatter chunk
constexpr int NEB = (E + CE - 1) / CE;    // 196
constexpr int SLOT = 6208;                // 4096 exp + sigma + 8-align pad
static_assert(N <= 65536, "u16 packing");
static_assert(N % 16 == 0, "16-row blocks need no bounds checks");

typedef _Float16 f16x8 __attribute__((ext_vector_type(8)));
typedef _Float16 f16x4 __attribute__((ext_vector_type(4)));
typedef _Float16 f16x2 __attribute__((ext_vector_type(2)));
typedef float f32x4 __attribute__((ext_vector_type(4)));
typedef unsigned short u16x8 __attribute__((ext_vector_type(8)));
typedef unsigned short u16x4 __attribute__((ext_vector_type(4)));

constexpr int CONVB = (N * 128 / 8 + 255) / 256;   // 3125 convert blocks
constexpr int MASKB = (N * 128) / (8 * 256);       // 3125 blocks per mask

// ---------------- merged setup + scatter + masks ---------------------------
// Wf[((ct*KB+kb)*64+lane)*8+j] = Wcat[ct*16+(lane&15)][kb*32+(lane>>4)*8+j]
__device__ inline void wfrag_build(int idx, int KB, const float* wl,
                                   const float* wr, _Float16* wf) {
  int j = idx & 7;
  int lane = (idx >> 3) & 63;
  int kb = (idx >> 9) % KB;
  int ct = (idx >> 9) / KB;
  int c = ct * 16 + (lane & 15);
  int k = kb * 32 + (lane >> 4) * 8 + j;
  float v = (k < 128) ? wl[c * 128 + k] : wr[c * 128 + (k - 128)];
  wf[idx] = (_Float16)v;
}

__global__ __launch_bounds__(256) void setup_scatter_kernel(
    const int* __restrict__ src, const int* __restrict__ dst,
    int* __restrict__ bcur, unsigned* __restrict__ T,
    const float* __restrict__ x,
    const float* __restrict__ u1, const float* __restrict__ u2,
    const float* __restrict__ wl0, const float* __restrict__ wr0,
    const float* __restrict__ wl1, const float* __restrict__ wr1,
    const float* __restrict__ wl2, const float* __restrict__ wr2,
    _Float16* __restrict__ HA, _Float16* __restrict__ wf0,
    _Float16* __restrict__ wf1, _Float16* __restrict__ wfZ,
    unsigned* __restrict__ mk1, unsigned* __restrict__ mk2) {
  __shared__ unsigned sorted[CE];
  __shared__ int hist[256], scan[256], excl[256], lcur[256], gbase[256];
  const int b = blockIdx.x;
  const int t = threadIdx.x;
  if (b < NEB) {                          // ---- scatter branch ----
    const int e0 = b * CE;
    const int nval = min(CE, E - e0);
    hist[t] = 0;
    __syncthreads();
    for (int i = t; i < nval; i += 256) atomicAdd(&hist[dst[e0 + i] >> 8], 1);
    __syncthreads();
    const int h = hist[t];
    scan[t] = h;
    __syncthreads();
    for (int off = 1; off < 256; off <<= 1) {
      int u = (t >= off) ? scan[t - off] : 0;
      __syncthreads();
      scan[t] += u;
      __syncthreads();
    }
    excl[t] = scan[t] - h;
    lcur[t] = scan[t] - h;
    gbase[t] = (t < NBUCK && h > 0) ? (t * SLOT + atomicAdd(&bcur[t], h)) : 0;
    __syncthreads();
    for (int i = t; i < nval; i += 256) {
      int e = e0 + i;
      int d = dst[e];
      int p = atomicAdd(&lcur[d >> 8], 1);
      sorted[p] = ((unsigned)d << 16) | (unsigned)src[e];
    }
    __syncthreads();
    for (int i = t; i < nval; i += 256) {
      unsigned pk = sorted[i];
      int bb = pk >> 24;                  // == dst>>8
      T[gbase[bb] + (i - excl[bb])] = pk;
    }
    return;
  }
  const int b2 = b - NEB;
  if (b2 < CONVB) {                       // ---- convert branch ----
    int i = b2 * 256 + t;                 // one thread per 8 elems
    if (i < N * 128 / 8) {
      float4 a = ((const float4*)x)[i * 2];
      float4 c = ((const float4*)x)[i * 2 + 1];
      f16x8 v;
      v[0] = (_Float16)a.x; v[1] = (_Float16)a.y; v[2] = (_Float16)a.z; v[3] = (_Float16)a.w;
      v[4] = (_Float16)c.x; v[5] = (_Float16)c.y; v[6] = (_Float16)c.z; v[7] = (_Float16)c.w;
      ((f16x8*)HA)[i] = v;
    }
  } else if (b2 < CONVB + 128) {          // wf0: [wl0|wr0], K=256
    wfrag_build((b2 - CONVB) * 256 + t, 8, wl0, wr0, wf0);
  } else if (b2 < CONVB + 256) {          // wf1: [wl1|wr1]
    wfrag_build((b2 - CONVB - 128) * 256 + t, 8, wl1, wr1, wf1);
  } else if (b2 < CONVB + 320) {          // wfZ: 8ct*4kb*512 = 16384 = 64 blk
    int idx = (b2 - CONVB - 256) * 256 + t;
    int j = idx & 7;
    int lane = (idx >> 3) & 63;
    int kb = (idx >> 9) & 3;
    int ct = idx >> 11;                   // 0..7
    int c = ct * 16 + (lane & 15);
    int k = kb * 32 + (lane >> 4) * 8 + j;
    float v = (c < 64) ? wl2[c * 128 + k] : wr2[(c - 64) * 128 + k];
    wfZ[idx] = (_Float16)v;
  } else {                                // ---- mask branch ----
    int mb = b2 - (CONVB + 320);
    const float* Us = (mb < MASKB) ? u1 : u2;
    unsigned* MKs = (mb < MASKB) ? mk1 : mk2;
    int bb = (mb < MASKB) ? mb : (mb - MASKB);
#pragma unroll
    for (int k = 0; k < 8; ++k) {
      int i = (bb * 8 + k) * 256 + t;     // wave covers 64 consecutive elems
      unsigned long long m = __ballot(Us[i] >= 0.3f);
      int lt = t & 63;
      if (lt == 0) MKs[i >> 5] = (unsigned)m;
      else if (lt == 32) MKs[i >> 5] = (unsigned)(m >> 32);
    }
  }
}

// Phase B: one block per bucket; offsets/degrees with 8-ALIGNED segments
// (u16 elist, ushort8 loads need e0%8==0), place edges as u16.
__global__ __launch_bounds__(256) void bucket_place_kernel(
    const unsigned* __restrict__ T, const int* __restrict__ bcur,
    int* __restrict__ offs, int* __restrict__ deg,
    unsigned short* __restrict__ elist) {
  __shared__ int dcnt[256], s[256], ncur[256];
  const int t = threadIdx.x;
  const int b = blockIdx.x;
  const int lo = b * SLOT;
  const int hi = lo + bcur[b];            // bcur holds per-bucket edge count
  dcnt[t] = 0;
  __syncthreads();
  for (int i = lo + t; i < hi; i += 256) atomicAdd(&dcnt[(T[i] >> 16) & 255], 1);
  __syncthreads();
  const int v = dcnt[t];
  const int pv = (v + 7) & ~7;            // 8-aligned segment length
  s[t] = pv;
  __syncthreads();
  for (int off = 1; off < 256; off <<= 1) {
    int u = (t >= off) ? s[t - off] : 0;
    __syncthreads();
    s[t] += u;
    __syncthreads();
  }
  const int base = lo + s[t] - pv;        // within-bucket exclusive + slab base
  const int node = b * 256 + t;
  if (node < N) { offs[node] = base; deg[node] = v; }
  ncur[t] = base;
  __syncthreads();
  for (int i = lo + t; i < hi; i += 256) {
    unsigned pk = T[i];
    int pos = atomicAdd(&ncur[(pk >> 16) & 255], 1);
    elist[pos] = (unsigned short)(pk & 0xffffu);
  }
}

// ---- widened gather-mean: half-wave per node, 16 lanes x f16x8 per edge,
//      2 edges per instruction; 8 f32 acc; shfl_xor(16) reduce per node.
//      Lane cl (=ll&15) covers cols 8*cl..8*cl+7; g (=ll>>4) is edge slot.
//      Result (g==0 lanes): f16x8 of mean cols -> Af[cl>>2][(cl&3)*16+r].
__device__ __forceinline__ void gather_mean_wide(
    const _Float16* __restrict__ H, const unsigned short* __restrict__ elist,
    int e0, int d, int g, int cl, float* acc /*[8], zeroed by caller*/) {
  const int e1 = e0 + d;
  int e = e0;
  for (; e + 16 <= e1; e += 16) {
    u16x8 q0 = *(const u16x8*)(elist + e);
    u16x8 q1 = *(const u16x8*)(elist + e + 8);
    int s[16] = {q0[0], q0[1], q0[2], q0[3], q0[4], q0[5], q0[6], q0[7],
                 q1[0], q1[1], q1[2], q1[3], q1[4], q1[5], q1[6], q1[7]};
    f16x8 v[8];
#pragma unroll
    for (int u = 0; u < 8; ++u)
      v[u] = *(const f16x8*)(H + (size_t)s[2 * u + g] * 128 + cl * 8);
#pragma unroll
    for (int u = 0; u < 8; ++u)
#pragma unroll
      for (int j = 0; j < 8; ++j) acc[j] += (float)v[u][j];
  }
  for (; e + 2 <= e1; e += 2) {
    int s0 = elist[e + g];
    f16x8 v = *(const f16x8*)(H + (size_t)s0 * 128 + cl * 8);
#pragma unroll
    for (int j = 0; j < 8; ++j) acc[j] += (float)v[j];
  }
  if (e < e1 && g == 0) {                 // odd leftover: group 0 only
    f16x8 v = *(const f16x8*)(H + (size_t)elist[e] * 128 + cl * 8);
#pragma unroll
    for (int j = 0; j < 8; ++j) acc[j] += (float)v[j];
  }
#pragma unroll
  for (int j = 0; j < 8; ++j) acc[j] += __shfl_xor(acc[j], 16);
}

// ---------------- fused layer 0: gather-mean -> LDS frags -> MFMA GEMM ----
__global__ __launch_bounds__(256, 6) void fused_layer_kernel(
    const _Float16* __restrict__ H, const int* __restrict__ offs,
    const int* __restrict__ deg, const unsigned short* __restrict__ elist,
    const _Float16* __restrict__ Wf, const float* __restrict__ bias,
    const unsigned* __restrict__ MK, _Float16* __restrict__ outp) {
  __shared__ __align__(16) _Float16 Af[8][64][8];      // [kb][lane][j] 8 KB
  const int t = threadIdx.x;
  const int rowbase = blockIdx.x * 16;

  // phase 1a: own H rows -> Af[4..7]
  {
    int r = t >> 4, o = t & 15;           // r: 0..15 row, o: 0..15 octet
    f16x8 v = *(const f16x8*)(H + (size_t)(rowbase + r) * 128 + o * 8);
    *(f16x8*)&Af[4 + (o >> 2)][(o & 3) * 16 + r][0] = v;
  }

  // phase 1b: widened gather-mean -> Af[0..3]
  {
    const int hw = t >> 5;                // half-wave 0..7
    const int ll = t & 31;
    const int g = ll >> 4;                // edge slot 0/1
    const int cl = ll & 15;               // cols 8*cl..8*cl+7
#pragma unroll 1
    for (int i = 0; i < 2; ++i) {
      int r = hw * 2 + i;
      int node = rowbase + r;
      float acc[8] = {0.f, 0.f, 0.f, 0.f, 0.f, 0.f, 0.f, 0.f};
      const int d = deg[node];
      gather_mean_wide(H, elist, offs[node], d, g, cl, acc);
      if (g == 0) {
        float inv = 1.0f / (float)max(d, 1);
        f16x8 o;
#pragma unroll
        for (int j = 0; j < 8; ++j) o[j] = (_Float16)(acc[j] * inv);
        *(f16x8*)&Af[cl >> 2][(cl & 3) * 16 + r][0] = o;
      }
    }
  }
  __syncthreads();

  // phase 2: GEMM. Wave w covers cols w*32..w*32+31; 16 rows.
  const int lane = t & 63;
  const int w = t >> 6;
  const int n16 = lane & 15;
  const int qq = lane >> 4;
  const int colbase = w * 32;

  f32x4 acc[2];
  acc[0] = (f32x4){0.f, 0.f, 0.f, 0.f};
  acc[1] = (f32x4){0.f, 0.f, 0.f, 0.f};

#pragma unroll
  for (int kb = 0; kb < 8; ++kb) {
    f16x8 a = *(const f16x8*)&Af[kb][lane][0];
#pragma unroll
    for (int ct = 0; ct < 2; ++ct) {
      const int ctg = w * 2 + ct;
      f16x8 b = *(const f16x8*)(Wf + ((size_t)(ctg * 8 + kb) * 64 + lane) * 8);
      acc[ct] = __builtin_amdgcn_mfma_f32_16x16x32_f16(a, b, acc[ct], 0, 0, 0);
    }
  }

  // C/D layout: col = lane&15, row = (lane>>4)*4 + reg
#pragma unroll
  for (int r = 0; r < 4; ++r) {
    int row = rowbase + qq * 4 + r;
    unsigned mw = MK[(size_t)row * 4 + w];
#pragma unroll
    for (int ct = 0; ct < 2; ++ct) {
      const int col = colbase + ct * 16 + n16;
      float v = fmaxf(acc[ct][r] + bias[col], 0.f);
      v = ((mw >> (ct * 16 + n16)) & 1u) ? v * (1.0f / 0.7f) : 0.0f;
      outp[(size_t)row * 128 + col] = (_Float16)v;
    }
  }
}

// ---------------- fused layer 1 + layer-2 GEMM ----------------------------
__global__ __launch_bounds__(256, 6) void fused_layerZ_kernel(
    const _Float16* __restrict__ H, const int* __restrict__ offs,
    const int* __restrict__ deg, const unsigned short* __restrict__ elist,
    const _Float16* __restrict__ Wf, const float* __restrict__ bias,
    const unsigned* __restrict__ MK, const _Float16* __restrict__ WfZ,
    const float* __restrict__ bl2, _Float16* __restrict__ Y2,
    float* __restrict__ F) {
  __shared__ __align__(16) _Float16 Af[8][64][8];      // 8 KB
  __shared__ __align__(16) _Float16 Zf[16][136];       // 4.25 KB
  const int t = threadIdx.x;
  const int rowbase = blockIdx.x * 16;

  {
    int r = t >> 4, o = t & 15;
    f16x8 v = *(const f16x8*)(H + (size_t)(rowbase + r) * 128 + o * 8);
    *(f16x8*)&Af[4 + (o >> 2)][(o & 3) * 16 + r][0] = v;
  }

  {
    const int hw = t >> 5;
    const int ll = t & 31;
    const int g = ll >> 4;
    const int cl = ll & 15;
#pragma unroll 1
    for (int i = 0; i < 2; ++i) {
      int r = hw * 2 + i;
      int node = rowbase + r;
      float acc[8] = {0.f, 0.f, 0.f, 0.f, 0.f, 0.f, 0.f, 0.f};
      const int d = deg[node];
      gather_mean_wide(H, elist, offs[node], d, g, cl, acc);
      if (g == 0) {
        float inv = 1.0f / (float)max(d, 1);
        f16x8 o;
#pragma unroll
        for (int j = 0; j < 8; ++j) o[j] = (_Float16)(acc[j] * inv);
        *(f16x8*)&Af[cl >> 2][(cl & 3) * 16 + r][0] = o;
      }
    }
  }
  __syncthreads();

  const int lane = t & 63;
  const int w = t >> 6;
  const int n16 = lane & 15;
  const int qq = lane >> 4;
  const int colbase = w * 32;

  f32x4 acc[2];
  acc[0] = (f32x4){0.f, 0.f, 0.f, 0.f};
  acc[1] = (f32x4){0.f, 0.f, 0.f, 0.f};

#pragma unroll
  for (int kb = 0; kb < 8; ++kb) {
    f16x8 a = *(const f16x8*)&Af[kb][lane][0];
#pragma unroll
    for (int ct = 0; ct < 2; ++ct) {
      const int ctg = w * 2 + ct;
      f16x8 b = *(const f16x8*)(Wf + ((size_t)(ctg * 8 + kb) * 64 + lane) * 8);
      acc[ct] = __builtin_amdgcn_mfma_f32_16x16x32_f16(a, b, acc[ct], 0, 0, 0);
    }
  }

  // epilogue: h1 = dropout(relu(acc+bias)) -> Zf
#pragma unroll
  for (int r = 0; r < 4; ++r) {
    int row = qq * 4 + r;                 // local 0..15
    unsigned mw = MK[(size_t)(rowbase + row) * 4 + w];
#pragma unroll
    for (int ct = 0; ct < 2; ++ct) {
      const int col = colbase + ct * 16 + n16;
      float v = fmaxf(acc[ct][r] + bias[col], 0.f);
      v = ((mw >> (ct * 16 + n16)) & 1u) ? v * (1.0f / 0.7f) : 0.0f;
      Zf[row][col] = (_Float16)v;
    }
  }
  __syncthreads();

  // layer-2 GEMM: A = Zf rows (K=128), B = WfZ
  f32x4 az[2];
  az[0] = (f32x4){0.f, 0.f, 0.f, 0.f};
  az[1] = (f32x4){0.f, 0.f, 0.f, 0.f};
#pragma unroll
  for (int kb = 0; kb < 4; ++kb) {
    f16x8 a = *(const f16x8*)&Zf[n16][kb * 32 + qq * 8];
#pragma unroll
    for (int ct = 0; ct < 2; ++ct) {
      const int ctg = w * 2 + ct;
      f16x8 b = *(const f16x8*)(WfZ + ((size_t)(ctg * 4 + kb) * 64 + lane) * 8);
      az[ct] = __builtin_amdgcn_mfma_f32_16x16x32_f16(a, b, az[ct], 0, 0, 0);
    }
  }
#pragma unroll
  for (int ct = 0; ct < 2; ++ct) {
    const int col = colbase + ct * 16 + n16;   // 0..127
#pragma unroll
    for (int r = 0; r < 4; ++r) {
      int row = rowbase + qq * 4 + r;
      float v = az[ct][r];
      if (col < 64) Y2[(size_t)row * 64 + col] = (_Float16)v;
      else F[(size_t)row * 64 + (col - 64)] = v + bl2[col - 64];
    }
  }
}

// ---------------- gather64 + final add: out = F + mean(Y2[nbrs]) ----------
// Widened: 16 lanes x f16x4 per edge (one 128B row), 2 edges/instr.
__global__ __launch_bounds__(256, 8) void gather64_add_kernel(
    const _Float16* __restrict__ Y2, const float* __restrict__ F,
    const int* __restrict__ offs, const int* __restrict__ deg,
    const unsigned short* __restrict__ elist, float* __restrict__ out) {
  int node = blockIdx.x * 8 + (threadIdx.x >> 5);
  if (node >= N) return;
  const int ll = threadIdx.x & 31;
  const int g = ll >> 4;                  // edge slot 0/1
  const int cl = ll & 15;                 // cols 4*cl..4*cl+3
  const int e0 = offs[node];              // e0 % 8 == 0
  const int d = deg[node];
  const int e1 = e0 + d;
  float a0 = 0.f, a1 = 0.f, a2 = 0.f, a3 = 0.f;
  int e = e0;
  for (; e + 16 <= e1; e += 16) {
    u16x8 q0 = *(const u16x8*)(elist + e);
    u16x8 q1 = *(const u16x8*)(elist + e + 8);
    int s[16] = {q0[0], q0[1], q0[2], q0[3], q0[4], q0[5], q0[6], q0[7],
                 q1[0], q1[1], q1[2], q1[3], q1[4], q1[5], q1[6], q1[7]};
    f16x4 v[8];
#pragma unroll
    for (int u = 0; u < 8; ++u)
      v[u] = *(const f16x4*)(Y2 + (size_t)s[2 * u + g] * 64 + cl * 4);
#pragma unroll
    for (int u = 0; u < 8; ++u) {
      a0 += (float)v[u][0]; a1 += (float)v[u][1];
      a2 += (float)v[u][2]; a3 += (float)v[u][3];
    }
  }
  for (; e + 2 <= e1; e += 2) {
    int s0 = elist[e + g];
    f16x4 v = *(const f16x4*)(Y2 + (size_t)s0 * 64 + cl * 4);
    a0 += (float)v[0]; a1 += (float)v[1];
    a2 += (float)v[2]; a3 += (float)v[3];
  }
  if (e < e1 && g == 0) {                 // odd leftover: group 0 only
    f16x4 v = *(const f16x4*)(Y2 + (size_t)elist[e] * 64 + cl * 4);
    a0 += (float)v[0]; a1 += (float)v[1];
    a2 += (float)v[2]; a3 += (float)v[3];
  }
  a0 += __shfl_xor(a0, 16);
  a1 += __shfl_xor(a1, 16);
  a2 += __shfl_xor(a2, 16);
  a3 += __shfl_xor(a3, 16);
  if (g == 0) {
    float inv = 1.0f / (float)max(d, 1);
    float4 f = ((const float4*)(F + (size_t)node * 64))[cl];
    float4 o;
    o.x = f.x + a0 * inv;
    o.y = f.y + a1 * inv;
    o.z = f.z + a2 * inv;
    o.w = f.w + a3 * inv;
    ((float4*)(out + (size_t)node * 64))[cl] = o;
  }
}

extern "C" void kernel_launch(void* const* d_in, const int* in_sizes, int n_in,
                              void* d_out, int out_size, void* d_ws, size_t ws_size,
                              hipStream_t stream) {
  const float* x   = (const float*)d_in[0];
  const float* u1  = (const float*)d_in[1];
  const float* u2  = (const float*)d_in[2];
  const float* wl0 = (const float*)d_in[3];
  const float* bl0 = (const float*)d_in[4];
  const float* wr0 = (const float*)d_in[5];
  const float* wl1 = (const float*)d_in[6];
  const float* bl1 = (const float*)d_in[7];
  const float* wr1 = (const float*)d_in[8];
  const float* wl2 = (const float*)d_in[9];
  const float* bl2 = (const float*)d_in[10];
  const float* wr2 = (const float*)d_in[11];
  const int* edge  = (const int*)d_in[12];
  const int* src = edge;
  const int* dst = edge + E;

  // workspace layout
  _Float16* HA  = (_Float16*)d_ws;                 // N x 128 f16
  _Float16* HB  = HA + (size_t)N * 128;            // N x 128 f16
  _Float16* Y2  = HB + (size_t)N * 128;            // N x 64 f16
  float* F      = (float*)(Y2 + (size_t)N * 64);   // N x 64 f32
  int* offs     = (int*)(F + (size_t)N * 64);      // N
  int* deg      = offs + N;                        // N
  unsigned short* elist = (unsigned short*)(deg + N);  // NBUCK*SLOT u16
  unsigned* T   = (unsigned*)(elist + NBUCK * SLOT);   // NBUCK*SLOT u32
  int* bcur     = (int*)(T + NBUCK * SLOT);        // NBUCK (counts)
  uintptr_t p = (uintptr_t)(bcur + NBUCK);
  p = (p + 15) & ~(uintptr_t)15;
  _Float16* wf0 = (_Float16*)p;                    // 8*8*512
  _Float16* wf1 = wf0 + 8 * 8 * 512;
  _Float16* wfZ = wf1 + 8 * 8 * 512;               // 8*4*512
  unsigned* mk1 = (unsigned*)(wfZ + 8 * 4 * 512);  // N*4 u32 (bit mask)
  unsigned* mk2 = mk1 + (size_t)N * 4;             // N*4 u32

  // 0) bcur counts = 0
  hipMemsetAsync(bcur, 0, NBUCK * sizeof(int), stream);
  // 1) merged setup + scatter + masks
  setup_scatter_kernel<<<NEB + CONVB + 320 + 2 * MASKB, 256, 0, stream>>>(
      src, dst, bcur, T, x, u1, u2, wl0, wr0, wl1, wr1, wl2, wr2,
      HA, wf0, wf1, wfZ, mk1, mk2);
  // 2) place
  bucket_place_kernel<<<NBUCK, 256, 0, stream>>>(T, bcur, offs, deg, elist);

  const int GM16 = N / 16;             // 3125 fused-layer blocks
  const int GG64 = (N + 7) / 8;        // half-wave per node

  // ---- Layer 0 (fused gather+GEMM) ----
  fused_layer_kernel<<<GM16, 256, 0, stream>>>(HA, offs, deg, elist, wf0, bl0,
                                               mk1, HB);
  // ---- Layer 1 + Layer-2 GEMM (fused; h1 never hits global) ----
  fused_layerZ_kernel<<<GM16, 256, 0, stream>>>(HB, offs, deg, elist, wf1, bl1,
                                                mk2, wfZ, bl2, Y2, F);
  // ---- Layer 2 gather + add ----
  gather64_add_kernel<<<GG64, 256, 0, stream>>>(Y2, F, offs, deg, elist,
                                                (float*)d_out);
}